// Round 2
// baseline (1137.335 us; speedup 1.0000x reference)
//
#include <hip/hip_runtime.h>
#include <hip/hip_bf16.h>
#include <stdint.h>

// Problem dims
#define Dd 1024
#define Ee 8
#define Ff 2816
#define Tt 8192    // B*S tokens
#define Pp 16384   // Tt * K pairs

// GEMM tiling
#define BM 128
#define BN 128
#define BKK 64
#define NT1 22             // F/BN
#define NT2 8              // D/BN
#define MAXT 136           // max M-tiles: Pp/BM + Ee (worst-case partial tiles)

using bf16x8 = __attribute__((ext_vector_type(8))) short;
using f32x4  = __attribute__((ext_vector_type(4))) float;

__device__ __forceinline__ uint16_t f2bf(float f) {
    union { float f; uint32_t u; } v; v.f = f;
    return (uint16_t)((v.u + 0x7fffu + ((v.u >> 16) & 1u)) >> 16);
}
__device__ __forceinline__ uint32_t pack2(float a, float b) {
    return (uint32_t)f2bf(a) | ((uint32_t)f2bf(b) << 16);
}
__device__ __forceinline__ uint4 pack8(float4 a, float4 b) {
    uint4 r; r.x = pack2(a.x, a.y); r.y = pack2(a.z, a.w);
    r.z = pack2(b.x, b.y); r.w = pack2(b.z, b.w); return r;
}
// XOR swizzle within a 128B LDS row (G4): spreads 16B slots across banks
__device__ __forceinline__ int swz(int row, int cb) {
    return row * 128 + (cb ^ ((row & 7) << 4));
}

// ---------------- Router: logits, top-2, softmax usage ----------------
__global__ __launch_bounds__(256) void router_kernel(
    const float* __restrict__ x, const float* __restrict__ gw,
    float* __restrict__ usage_bank, int* __restrict__ counts,
    int* __restrict__ tok_i, float* __restrict__ tok_w)
{
    __shared__ float us[Ee];
    int tid = threadIdx.x;
    if (tid < Ee) us[tid] = 0.f;
    __syncthreads();
    int wave = tid >> 6, lane = tid & 63;
    int t = blockIdx.x * 4 + wave;

    float xr[16];
    const float* xp = x + (size_t)t * Dd;
    #pragma unroll
    for (int j = 0; j < 16; ++j) xr[j] = xp[lane + 64 * j];

    float logits[Ee];
    #pragma unroll
    for (int e = 0; e < Ee; ++e) {
        const float* gp = gw + e * Dd;
        float s = 0.f;
        #pragma unroll
        for (int j = 0; j < 16; ++j) s += xr[j] * gp[lane + 64 * j];
        #pragma unroll
        for (int m = 1; m < 64; m <<= 1) s += __shfl_xor(s, m, 64);
        logits[e] = s;
    }
    // top-2 (strict > keeps lower index on ties, matching lax.top_k)
    float v1 = -1e30f, v2 = -1e30f; int i1 = 0, i2 = 0;
    #pragma unroll
    for (int e = 0; e < Ee; ++e) {
        float l = logits[e];
        if (l > v1) { v2 = v1; i2 = i1; v1 = l; i1 = e; }
        else if (l > v2) { v2 = l; i2 = e; }
    }
    float ex2 = expf(v2 - v1);
    float w1 = 1.f / (1.f + ex2);
    float w2 = ex2 * w1;
    // full softmax for expert usage (aux loss)
    float p[Ee]; float se = 0.f;
    #pragma unroll
    for (int e = 0; e < Ee; ++e) { p[e] = expf(logits[e] - v1); se += p[e]; }
    float inv = 1.f / se;
    if (lane == 0) {
        #pragma unroll
        for (int e = 0; e < Ee; ++e) atomicAdd(&us[e], p[e] * inv);
        atomicAdd(&counts[i1], 1);
        atomicAdd(&counts[i2], 1);
        tok_i[t * 2] = i1; tok_i[t * 2 + 1] = i2;
        tok_w[t * 2] = w1; tok_w[t * 2 + 1] = w2;
    }
    __syncthreads();
    if (tid < Ee) atomicAdd(&usage_bank[(blockIdx.x & 63) * Ee + tid], us[tid]);
}

// ---------------- Scan: aux loss + segment offsets + tile list ----------------
__global__ void scan_kernel(const float* __restrict__ usage_bank,
                            const int* __restrict__ counts,
                            int* __restrict__ seg_off, int* __restrict__ cursor,
                            int* __restrict__ ntiles, int* __restrict__ tile_e,
                            int* __restrict__ tile_row0, float* __restrict__ out_aux)
{
    int tid = threadIdx.x;
    __shared__ float us[Ee];
    if (tid < Ee) {
        float s = 0.f;
        for (int b = 0; b < 64; ++b) s += usage_bank[b * Ee + tid];
        us[tid] = s / (float)Tt;
    }
    __syncthreads();
    if (tid == 0) {
        float aux = 0.f;
        for (int e = 0; e < Ee; ++e) { float d = us[e] - 0.125f; aux += d * d; }
        *out_aux = aux;
        int off = 0;
        for (int e = 0; e < Ee; ++e) { seg_off[e] = off; cursor[e] = off; off += counts[e]; }
        seg_off[Ee] = off;  // == Pp
        int ti = 0;
        for (int e = 0; e < Ee; ++e) {
            int so = seg_off[e], cnt = counts[e];
            for (int r = 0; r < cnt; r += BM) { tile_e[ti] = e; tile_row0[ti] = so + r; ++ti; }
        }
        *ntiles = ti;   // <= MAXT
    }
}

// ---------------- Build per-expert pair lists ----------------
__global__ __launch_bounds__(256) void build_kernel(
    const int* __restrict__ tok_i, const float* __restrict__ tok_w,
    int* __restrict__ cursor, int* __restrict__ token_id, float* __restrict__ pair_w)
{
    int t = blockIdx.x * 256 + threadIdx.x;
    if (t >= Tt) return;
    int i1 = tok_i[t * 2], i2 = tok_i[t * 2 + 1];
    int s1 = atomicAdd(&cursor[i1], 1);
    token_id[s1] = t; pair_w[s1] = tok_w[t * 2];
    int s2 = atomicAdd(&cursor[i2], 1);
    token_id[s2] = t; pair_w[s2] = tok_w[t * 2 + 1];
}

// ---------------- fp32 -> bf16 weight conversion ----------------
__global__ __launch_bounds__(256) void conv_kernel(
    const float* __restrict__ src, uint16_t* __restrict__ dst, long long n)
{
    long long i = ((long long)blockIdx.x * 256 + threadIdx.x) * 8;
    if (i >= n) return;
    const float4* s = (const float4*)(src + i);
    float4 a = s[0], b = s[1];
    *(uint4*)(dst + i) = pack8(a, b);
}

// ---------------- GEMM1: fused gather + gate+up, h = silu(g)*u ----------------
template<bool PRECONV>
__global__ __launch_bounds__(256) void gemm1_kernel(
    const float* __restrict__ x, const int* __restrict__ token_id,
    const float* __restrict__ wgate_f, const float* __restrict__ wup_f,
    const uint16_t* __restrict__ wgate_b, const uint16_t* __restrict__ wup_b,
    const int* __restrict__ seg_off, const int* __restrict__ tile_e,
    const int* __restrict__ tile_row0, const int* __restrict__ ntiles,
    uint16_t* __restrict__ hbuf, int tile0)
{
    int bx = blockIdx.x;
    int lt = bx / NT1, nt = bx - lt * NT1;
    int tidx = tile0 + lt;
    if (tidx >= *ntiles) return;
    int e = tile_e[tidx];
    int row0 = tile_row0[tidx];
    int rows = seg_off[e + 1] - row0; if (rows > BM) rows = BM;
    int slot = lt * BM;  // chunk-local hbuf row base

    __shared__ uint4 ldsbuf[(BM * BKK * 2 * 3) / 16];
    char* smA = (char*)ldsbuf;
    char* smG = smA + BM * BKK * 2;
    char* smU = smA + BM * BKK * 2 * 2;

    int tid = threadIdx.x;
    int row = tid >> 1, half = tid & 1;
    int wcolb = half * 64;
    int prc = row0 + (row < rows ? row : rows - 1);
    int tok = token_id[prc];
    const float* aSrc = x + (size_t)tok * Dd + half * 32;
    size_t wbase = ((size_t)e * Ff + (nt * BN + row)) * Dd + half * 32;

    int lane = tid & 63, wv = tid >> 6;
    int wr = wv >> 1, wc = wv & 1;

    f32x4 accg[4][4], accu[4][4];
    f32x4 zero4 = {0.f, 0.f, 0.f, 0.f};
    #pragma unroll
    for (int m = 0; m < 4; ++m)
        #pragma unroll
        for (int n = 0; n < 4; ++n) { accg[m][n] = zero4; accu[m][n] = zero4; }

    for (int ks = 0; ks < Dd / BKK; ++ks) {
        __syncthreads();
        {   // stage A: gather row of x, fp32 -> bf16
            const float4* s = (const float4*)(aSrc + ks * BKK);
            float4 f0 = s[0], f1 = s[1], f2 = s[2], f3 = s[3];
            float4 f4 = s[4], f5 = s[5], f6 = s[6], f7 = s[7];
            *(uint4*)(smA + swz(row, wcolb + 0))  = pack8(f0, f1);
            *(uint4*)(smA + swz(row, wcolb + 16)) = pack8(f2, f3);
            *(uint4*)(smA + swz(row, wcolb + 32)) = pack8(f4, f5);
            *(uint4*)(smA + swz(row, wcolb + 48)) = pack8(f6, f7);
        }
        if (PRECONV) {
            const uint4* sg = (const uint4*)(wgate_b + wbase + ks * BKK);
            uint4 g0 = sg[0], g1 = sg[1], g2 = sg[2], g3 = sg[3];
            *(uint4*)(smG + swz(row, wcolb + 0))  = g0;
            *(uint4*)(smG + swz(row, wcolb + 16)) = g1;
            *(uint4*)(smG + swz(row, wcolb + 32)) = g2;
            *(uint4*)(smG + swz(row, wcolb + 48)) = g3;
            const uint4* su = (const uint4*)(wup_b + wbase + ks * BKK);
            uint4 u0 = su[0], u1 = su[1], u2 = su[2], u3 = su[3];
            *(uint4*)(smU + swz(row, wcolb + 0))  = u0;
            *(uint4*)(smU + swz(row, wcolb + 16)) = u1;
            *(uint4*)(smU + swz(row, wcolb + 32)) = u2;
            *(uint4*)(smU + swz(row, wcolb + 48)) = u3;
        } else {
            const float4* sg = (const float4*)(wgate_f + wbase + ks * BKK);
            float4 a0 = sg[0], a1 = sg[1], a2 = sg[2], a3 = sg[3];
            float4 a4 = sg[4], a5 = sg[5], a6 = sg[6], a7 = sg[7];
            *(uint4*)(smG + swz(row, wcolb + 0))  = pack8(a0, a1);
            *(uint4*)(smG + swz(row, wcolb + 16)) = pack8(a2, a3);
            *(uint4*)(smG + swz(row, wcolb + 32)) = pack8(a4, a5);
            *(uint4*)(smG + swz(row, wcolb + 48)) = pack8(a6, a7);
            const float4* su = (const float4*)(wup_f + wbase + ks * BKK);
            float4 b0 = su[0], b1 = su[1], b2 = su[2], b3 = su[3];
            float4 b4 = su[4], b5 = su[5], b6 = su[6], b7 = su[7];
            *(uint4*)(smU + swz(row, wcolb + 0))  = pack8(b0, b1);
            *(uint4*)(smU + swz(row, wcolb + 16)) = pack8(b2, b3);
            *(uint4*)(smU + swz(row, wcolb + 32)) = pack8(b4, b5);
            *(uint4*)(smU + swz(row, wcolb + 48)) = pack8(b6, b7);
        }
        __syncthreads();
        #pragma unroll
        for (int kk = 0; kk < 2; ++kk) {
            int cb = kk * 64 + ((lane >> 4) << 4);
            bf16x8 a[4], bg[4], bu[4];
            #pragma unroll
            for (int m = 0; m < 4; ++m)
                a[m] = *(const bf16x8*)(smA + swz(wr * 64 + m * 16 + (lane & 15), cb));
            #pragma unroll
            for (int n = 0; n < 4; ++n)
                bg[n] = *(const bf16x8*)(smG + swz(wc * 64 + n * 16 + (lane & 15), cb));
            #pragma unroll
            for (int n = 0; n < 4; ++n)
                bu[n] = *(const bf16x8*)(smU + swz(wc * 64 + n * 16 + (lane & 15), cb));
            #pragma unroll
            for (int m = 0; m < 4; ++m)
                #pragma unroll
                for (int n = 0; n < 4; ++n) {
                    accg[m][n] = __builtin_amdgcn_mfma_f32_16x16x32_bf16(a[m], bg[n], accg[m][n], 0, 0, 0);
                    accu[m][n] = __builtin_amdgcn_mfma_f32_16x16x32_bf16(a[m], bu[n], accu[m][n], 0, 0, 0);
                }
        }
    }
    // epilogue: h = silu(g) * u -> bf16 into chunk-local hbuf
    int r0 = wr * 64 + ((lane >> 4) << 2);
    int c0 = nt * BN + wc * 64 + (lane & 15);
    #pragma unroll
    for (int m = 0; m < 4; ++m) {
        #pragma unroll
        for (int r = 0; r < 4; ++r) {
            int rr = r0 + m * 16 + r;
            if (rr < rows) {
                uint16_t* hp = hbuf + (size_t)(slot + rr) * Ff + c0;
                #pragma unroll
                for (int n = 0; n < 4; ++n) {
                    float g = accg[m][n][r];
                    float u = accu[m][n][r];
                    float h = g * u / (1.f + expf(-g));
                    hp[n * 16] = f2bf(h);
                }
            }
        }
    }
}

// ---------------- GEMM2: out += w * (h @ wd^T) ----------------
template<bool PRECONV>
__global__ __launch_bounds__(256) void gemm2_kernel(
    const uint16_t* __restrict__ hbuf,
    const float* __restrict__ wdown_f, const uint16_t* __restrict__ wdown_b,
    const int* __restrict__ seg_off, const int* __restrict__ tile_e,
    const int* __restrict__ tile_row0, const int* __restrict__ ntiles,
    const int* __restrict__ token_id, const float* __restrict__ pair_w,
    float* __restrict__ out, int tile0)
{
    int bx = blockIdx.x;
    int lt = bx / NT2, nt = bx - lt * NT2;
    int tidx = tile0 + lt;
    if (tidx >= *ntiles) return;
    int e = tile_e[tidx];
    int row0 = tile_row0[tidx];
    int rows = seg_off[e + 1] - row0; if (rows > BM) rows = BM;
    int slot = lt * BM;

    __shared__ uint4 ldsbuf[(BM * BKK * 2 * 2) / 16];
    char* smA = (char*)ldsbuf;
    char* smB = smA + BM * BKK * 2;

    int tid = threadIdx.x;
    int row = tid >> 1, half = tid & 1;
    int wcolb = half * 64;
    const uint16_t* aSrc = hbuf + (size_t)(slot + row) * Ff + half * 32;
    size_t wbase = ((size_t)e * Dd + (nt * BN + row)) * Ff + half * 32;

    int lane = tid & 63, wv = tid >> 6;
    int wr = wv >> 1, wc = wv & 1;

    f32x4 acc[4][4];
    f32x4 zero4 = {0.f, 0.f, 0.f, 0.f};
    #pragma unroll
    for (int m = 0; m < 4; ++m)
        #pragma unroll
        for (int n = 0; n < 4; ++n) acc[m][n] = zero4;

    for (int ks = 0; ks < Ff / BKK; ++ks) {   // 44 steps
        __syncthreads();
        {   // stage A (bf16 h)
            const uint4* s = (const uint4*)(aSrc + ks * BKK);
            uint4 v0 = s[0], v1 = s[1], v2 = s[2], v3 = s[3];
            *(uint4*)(smA + swz(row, wcolb + 0))  = v0;
            *(uint4*)(smA + swz(row, wcolb + 16)) = v1;
            *(uint4*)(smA + swz(row, wcolb + 32)) = v2;
            *(uint4*)(smA + swz(row, wcolb + 48)) = v3;
        }
        if (PRECONV) {
            const uint4* sb = (const uint4*)(wdown_b + wbase + ks * BKK);
            uint4 v0 = sb[0], v1 = sb[1], v2 = sb[2], v3 = sb[3];
            *(uint4*)(smB + swz(row, wcolb + 0))  = v0;
            *(uint4*)(smB + swz(row, wcolb + 16)) = v1;
            *(uint4*)(smB + swz(row, wcolb + 32)) = v2;
            *(uint4*)(smB + swz(row, wcolb + 48)) = v3;
        } else {
            const float4* sb = (const float4*)(wdown_f + wbase + ks * BKK);
            float4 a0 = sb[0], a1 = sb[1], a2 = sb[2], a3 = sb[3];
            float4 a4 = sb[4], a5 = sb[5], a6 = sb[6], a7 = sb[7];
            *(uint4*)(smB + swz(row, wcolb + 0))  = pack8(a0, a1);
            *(uint4*)(smB + swz(row, wcolb + 16)) = pack8(a2, a3);
            *(uint4*)(smB + swz(row, wcolb + 32)) = pack8(a4, a5);
            *(uint4*)(smB + swz(row, wcolb + 48)) = pack8(a6, a7);
        }
        __syncthreads();
        #pragma unroll
        for (int kk = 0; kk < 2; ++kk) {
            int cb = kk * 64 + ((lane >> 4) << 4);
            bf16x8 a[4], b[4];
            #pragma unroll
            for (int m = 0; m < 4; ++m)
                a[m] = *(const bf16x8*)(smA + swz(wr * 64 + m * 16 + (lane & 15), cb));
            #pragma unroll
            for (int n = 0; n < 4; ++n)
                b[n] = *(const bf16x8*)(smB + swz(wc * 64 + n * 16 + (lane & 15), cb));
            #pragma unroll
            for (int m = 0; m < 4; ++m)
                #pragma unroll
                for (int n = 0; n < 4; ++n)
                    acc[m][n] = __builtin_amdgcn_mfma_f32_16x16x32_bf16(a[m], b[n], acc[m][n], 0, 0, 0);
        }
    }
    // epilogue: atomic combine into out (exactly 2 commutative adds/element -> deterministic)
    int r0 = wr * 64 + ((lane >> 4) << 2);
    int c0 = nt * BN + wc * 64 + (lane & 15);
    #pragma unroll
    for (int m = 0; m < 4; ++m) {
        #pragma unroll
        for (int r = 0; r < 4; ++r) {
            int rr = r0 + m * 16 + r;
            if (rr < rows) {
                int pr = row0 + rr;
                int tok = token_id[pr];
                float w = pair_w[pr];
                float* op = out + (size_t)tok * Dd + c0;
                #pragma unroll
                for (int n = 0; n < 4; ++n)
                    atomicAdd(op + n * 16, w * acc[m][n][r]);
            }
        }
    }
}

// ---------------- Host launch ----------------
extern "C" void kernel_launch(void* const* d_in, const int* in_sizes, int n_in,
                              void* d_out, int out_size, void* d_ws, size_t ws_size,
                              hipStream_t stream)
{
    const float* x     = (const float*)d_in[0];
    const float* gw    = (const float*)d_in[1];
    const float* wgate = (const float*)d_in[2];
    const float* wup   = (const float*)d_in[3];
    const float* wdown = (const float*)d_in[4];
    float* out = (float*)d_out;

    char* ws = (char*)d_ws;
    // Control region layout (270336 bytes total)
    float* usage_bank = (float*)(ws);             // 2048 B
    int*   counts     = (int*)(ws + 2048);        // 32 B
    int*   seg_off    = (int*)(ws + 2112);        // 36 B
    int*   cursor     = (int*)(ws + 2176);        // 32 B
    int*   ntiles     = (int*)(ws + 2240);        // 4 B
    int*   tile_e     = (int*)(ws + 4096);        // 1024 B
    int*   tile_row0  = (int*)(ws + 5120);        // 1024 B
    int*   tok_i      = (int*)(ws + 8192);        // 65536 B
    float* tok_w      = (float*)(ws + 73728);     // 65536 B
    int*   token_id   = (int*)(ws + 139264);      // 65536 B
    float* pair_w     = (float*)(ws + 204800);    // 65536 B
    const size_t CTRL  = 270336;
    const size_t TILEB = (size_t)BM * Ff * 2;         // 720,896 B per h-tile
    const size_t WB3   = 3ull * Ee * Ff * Dd * 2;     // 138,412,032 B bf16 weights

    hipMemsetAsync(d_out, 0, (size_t)out_size * 4, stream);
    if (ws_size >= 4096) hipMemsetAsync(ws, 0, 4096, stream);
    if (ws_size < CTRL) return;   // cannot run at all; fail gracefully (no OOB)

    router_kernel<<<Tt / 4, 256, 0, stream>>>(x, gw, usage_bank, counts, tok_i, tok_w);
    scan_kernel<<<1, 64, 0, stream>>>(usage_bank, counts, seg_off, cursor,
                                      ntiles, tile_e, tile_row0, out + (out_size - 1));
    build_kernel<<<Tt / 256, 256, 0, stream>>>(tok_i, tok_w, cursor, token_id, pair_w);

    size_t avail = ws_size - CTRL;
    if (avail < TILEB) return;    // no room for even one h-tile; fail gracefully

    bool preconv = (avail >= WB3 + 32 * TILEB);
    uint16_t *wg_b = nullptr, *wu_b = nullptr, *wd_b = nullptr;
    uint16_t* hbuf;
    size_t hspace;
    if (preconv) {
        wg_b = (uint16_t*)(ws + CTRL);
        wu_b = wg_b + (size_t)Ee * Ff * Dd;
        wd_b = wu_b + (size_t)Ee * Ff * Dd;
        hbuf = (uint16_t*)(ws + CTRL + WB3);
        hspace = avail - WB3;
    } else {
        hbuf = (uint16_t*)(ws + CTRL);
        hspace = avail;
    }
    int Tc = (int)(hspace / TILEB);
    if (Tc > MAXT) Tc = MAXT;
    int nchunks = (MAXT + Tc - 1) / Tc;

    if (preconv) {
        long long n = (long long)Ee * Ff * Dd;   // 23,068,672 ; /2048 = 11264 blocks
        conv_kernel<<<11264, 256, 0, stream>>>(wgate, wg_b, n);
        conv_kernel<<<11264, 256, 0, stream>>>(wup,   wu_b, n);
        conv_kernel<<<11264, 256, 0, stream>>>(wdown, wd_b, n);
    }

    for (int c = 0; c < nchunks; ++c) {
        int tile0 = c * Tc;
        if (preconv) {
            gemm1_kernel<true><<<Tc * NT1, 256, 0, stream>>>(
                x, token_id, wgate, wup, wg_b, wu_b,
                seg_off, tile_e, tile_row0, ntiles, hbuf, tile0);
            gemm2_kernel<true><<<Tc * NT2, 256, 0, stream>>>(
                hbuf, wdown, wd_b, seg_off, tile_e, tile_row0, ntiles,
                token_id, pair_w, out, tile0);
        } else {
            gemm1_kernel<false><<<Tc * NT1, 256, 0, stream>>>(
                x, token_id, wgate, wup, wg_b, wu_b,
                seg_off, tile_e, tile_row0, ntiles, hbuf, tile0);
            gemm2_kernel<false><<<Tc * NT2, 256, 0, stream>>>(
                hbuf, wdown, wd_b, seg_off, tile_e, tile_row0, ntiles,
                token_id, pair_w, out, tile0);
        }
    }
}

// Round 3
// 932.828 us; speedup vs baseline: 1.2192x; 1.2192x over previous
//
#include <hip/hip_runtime.h>
#include <hip/hip_bf16.h>
#include <stdint.h>

// Problem dims
#define Dd 1024
#define Ee 8
#define Ff 2816
#define Tt 8192    // B*S tokens
#define Pp 16384   // Tt * K pairs

// GEMM tiling
#define BM 128
#define BN 128
#define BKK 64
#define NT1 22             // F/BN
#define NT2 8              // D/BN
#define MAXT 136           // max M-tiles: Pp/BM + Ee (worst-case partial tiles)

using bf16x8 = __attribute__((ext_vector_type(8))) short;
using f32x4  = __attribute__((ext_vector_type(4))) float;

__device__ __forceinline__ uint16_t f2bf(float f) {
    union { float f; uint32_t u; } v; v.f = f;
    return (uint16_t)((v.u + 0x7fffu + ((v.u >> 16) & 1u)) >> 16);
}
__device__ __forceinline__ uint32_t pack2(float a, float b) {
    return (uint32_t)f2bf(a) | ((uint32_t)f2bf(b) << 16);
}
__device__ __forceinline__ uint4 pack8(float4 a, float4 b) {
    uint4 r; r.x = pack2(a.x, a.y); r.y = pack2(a.z, a.w);
    r.z = pack2(b.x, b.y); r.w = pack2(b.z, b.w); return r;
}
// XOR swizzle within a 128B LDS row (G4): spreads 16B slots across banks
__device__ __forceinline__ int swz(int row, int cb) {
    return row * 128 + (cb ^ ((row & 7) << 4));
}
// async global->LDS, 16B per lane; LDS dest must be wave-uniform base (+lane*16 implicit)
__device__ __forceinline__ void gload16(const void* g, void* lds) {
    __builtin_amdgcn_global_load_lds(
        (const __attribute__((address_space(1))) uint32_t*)(uintptr_t)g,
        (__attribute__((address_space(3))) uint32_t*)(uintptr_t)lds,
        16, 0, 0);
}

// ---------------- Router: logits, top-2, softmax usage ----------------
__global__ __launch_bounds__(256) void router_kernel(
    const float* __restrict__ x, const float* __restrict__ gw,
    float* __restrict__ usage_bank, int* __restrict__ counts,
    int* __restrict__ tok_i, float* __restrict__ tok_w)
{
    __shared__ float us[Ee];
    int tid = threadIdx.x;
    if (tid < Ee) us[tid] = 0.f;
    __syncthreads();
    int wave = tid >> 6, lane = tid & 63;
    int t = blockIdx.x * 4 + wave;

    float xr[16];
    const float* xp = x + (size_t)t * Dd;
    #pragma unroll
    for (int j = 0; j < 16; ++j) xr[j] = xp[lane + 64 * j];

    float logits[Ee];
    #pragma unroll
    for (int e = 0; e < Ee; ++e) {
        const float* gp = gw + e * Dd;
        float s = 0.f;
        #pragma unroll
        for (int j = 0; j < 16; ++j) s += xr[j] * gp[lane + 64 * j];
        #pragma unroll
        for (int m = 1; m < 64; m <<= 1) s += __shfl_xor(s, m, 64);
        logits[e] = s;
    }
    // top-2 (strict > keeps lower index on ties, matching lax.top_k)
    float v1 = -1e30f, v2 = -1e30f; int i1 = 0, i2 = 0;
    #pragma unroll
    for (int e = 0; e < Ee; ++e) {
        float l = logits[e];
        if (l > v1) { v2 = v1; i2 = i1; v1 = l; i1 = e; }
        else if (l > v2) { v2 = l; i2 = e; }
    }
    float ex2 = expf(v2 - v1);
    float w1 = 1.f / (1.f + ex2);
    float w2 = ex2 * w1;
    // full softmax for expert usage (aux loss)
    float p[Ee]; float se = 0.f;
    #pragma unroll
    for (int e = 0; e < Ee; ++e) { p[e] = expf(logits[e] - v1); se += p[e]; }
    float inv = 1.f / se;
    if (lane == 0) {
        #pragma unroll
        for (int e = 0; e < Ee; ++e) atomicAdd(&us[e], p[e] * inv);
        atomicAdd(&counts[i1], 1);
        atomicAdd(&counts[i2], 1);
        tok_i[t * 2] = i1; tok_i[t * 2 + 1] = i2;
        tok_w[t * 2] = w1; tok_w[t * 2 + 1] = w2;
    }
    __syncthreads();
    if (tid < Ee) atomicAdd(&usage_bank[(blockIdx.x & 63) * Ee + tid], us[tid]);
}

// ---------------- Scan: aux loss + segment offsets + tile list ----------------
__global__ void scan_kernel(const float* __restrict__ usage_bank,
                            const int* __restrict__ counts,
                            int* __restrict__ seg_off, int* __restrict__ cursor,
                            int* __restrict__ ntiles, int* __restrict__ tile_e,
                            int* __restrict__ tile_row0, float* __restrict__ out_aux)
{
    int tid = threadIdx.x;
    __shared__ float us[Ee];
    if (tid < Ee) {
        float s = 0.f;
        for (int b = 0; b < 64; ++b) s += usage_bank[b * Ee + tid];
        us[tid] = s / (float)Tt;
    }
    __syncthreads();
    if (tid == 0) {
        float aux = 0.f;
        for (int e = 0; e < Ee; ++e) { float d = us[e] - 0.125f; aux += d * d; }
        *out_aux = aux;
        int off = 0;
        for (int e = 0; e < Ee; ++e) { seg_off[e] = off; cursor[e] = off; off += counts[e]; }
        seg_off[Ee] = off;  // == Pp
        int ti = 0;
        for (int e = 0; e < Ee; ++e) {
            int so = seg_off[e], cnt = counts[e];
            for (int r = 0; r < cnt; r += BM) { tile_e[ti] = e; tile_row0[ti] = so + r; ++ti; }
        }
        *ntiles = ti;   // <= MAXT
    }
}

// ---------------- Build per-expert pair lists ----------------
__global__ __launch_bounds__(256) void build_kernel(
    const int* __restrict__ tok_i, const float* __restrict__ tok_w,
    int* __restrict__ cursor, int* __restrict__ token_id, float* __restrict__ pair_w)
{
    int t = blockIdx.x * 256 + threadIdx.x;
    if (t >= Tt) return;
    int i1 = tok_i[t * 2], i2 = tok_i[t * 2 + 1];
    int s1 = atomicAdd(&cursor[i1], 1);
    token_id[s1] = t; pair_w[s1] = tok_w[t * 2];
    int s2 = atomicAdd(&cursor[i2], 1);
    token_id[s2] = t; pair_w[s2] = tok_w[t * 2 + 1];
}

// ---------------- Gather x rows -> bf16 Xg[pair, D] (4 rows/block) ----------------
__global__ __launch_bounds__(256) void gather_kernel(
    const float* __restrict__ x, const int* __restrict__ token_id,
    uint16_t* __restrict__ Xg)
{
    int wave = threadIdx.x >> 6, lane = threadIdx.x & 63;
    int r = blockIdx.x * 4 + wave;
    if (r >= Pp) return;
    int t = token_id[r];
    const float4* src = (const float4*)(x + (size_t)t * Dd) + lane * 4;
    float4 f0 = src[0], f1 = src[1], f2 = src[2], f3 = src[3];
    uint4* dst = (uint4*)(Xg + (size_t)r * Dd) + lane * 2;
    dst[0] = pack8(f0, f1);
    dst[1] = pack8(f2, f3);
}

// ---------------- fp32 -> bf16 weight conversion ----------------
__global__ __launch_bounds__(256) void conv_kernel(
    const float* __restrict__ src, uint16_t* __restrict__ dst, long long n)
{
    long long i = ((long long)blockIdx.x * 256 + threadIdx.x) * 8;
    if (i >= n) return;
    const float4* s = (const float4*)(src + i);
    float4 a = s[0], b = s[1];
    *(uint4*)(dst + i) = pack8(a, b);
}

// ---------------- GEMM1: gate+up, h = silu(g)*u ----------------
// PRECONV=true: A from pre-gathered bf16 Xg, B from bf16 weights, all staged via
// global_load_lds (linear LDS dest + inverse-swizzled global source, rule #21).
template<bool PRECONV>
__global__ __launch_bounds__(256) void gemm1_kernel(
    const float* __restrict__ x, const uint16_t* __restrict__ Xg,
    const int* __restrict__ token_id,
    const float* __restrict__ wgate_f, const float* __restrict__ wup_f,
    const uint16_t* __restrict__ wgate_b, const uint16_t* __restrict__ wup_b,
    const int* __restrict__ seg_off, const int* __restrict__ tile_e,
    const int* __restrict__ tile_row0, const int* __restrict__ ntiles,
    uint16_t* __restrict__ hbuf, int tile0)
{
    int bx = blockIdx.x;
    int lt = bx / NT1, nt = bx - lt * NT1;
    int tidx = tile0 + lt;
    if (tidx >= *ntiles) return;
    int e = tile_e[tidx];
    int row0 = tile_row0[tidx];
    int rows = seg_off[e + 1] - row0; if (rows > BM) rows = BM;
    int slot = lt * BM;  // chunk-local hbuf row base

    __shared__ uint4 ldsbuf[(BM * BKK * 2 * 3) / 16];
    char* smA = (char*)ldsbuf;
    char* smG = smA + BM * BKK * 2;
    char* smU = smA + BM * BKK * 2 * 2;

    int tid = threadIdx.x;
    int lane = tid & 63, wv = tid >> 6;
    int wr = wv >> 1, wc = wv & 1;

    f32x4 accg[4][4], accu[4][4];
    f32x4 zero4 = {0.f, 0.f, 0.f, 0.f};
    #pragma unroll
    for (int m = 0; m < 4; ++m)
        #pragma unroll
        for (int n = 0; n < 4; ++n) { accg[m][n] = zero4; accu[m][n] = zero4; }

    if (PRECONV) {
        // per-lane inverse-swizzled source addressing
        int lr = lane >> 3;                       // row within 8-row stripe
        int csw = ((lane & 7) ^ lr) * 8;          // source col chunk (elements)
        const uint16_t* aB = Xg + (size_t)(row0 + wv * 32 + lr) * Dd + csw;
        size_t wrow = (size_t)e * Ff + nt * BN + wv * 32 + lr;
        const uint16_t* gB = wgate_b + wrow * Dd + csw;
        const uint16_t* uB = wup_b   + wrow * Dd + csw;
        char* aL = smA + wv * 4096;
        char* gL = smG + wv * 4096;
        char* uL = smU + wv * 4096;

        for (int ks = 0; ks < Dd / BKK; ++ks) {
            __syncthreads();
            #pragma unroll
            for (int i = 0; i < 4; ++i) {
                gload16(aB + (size_t)i * 8 * Dd + ks * BKK, aL + i * 1024);
                gload16(gB + (size_t)i * 8 * Dd + ks * BKK, gL + i * 1024);
                gload16(uB + (size_t)i * 8 * Dd + ks * BKK, uL + i * 1024);
            }
            __syncthreads();
            #pragma unroll
            for (int kk = 0; kk < 2; ++kk) {
                int cb = kk * 64 + ((lane >> 4) << 4);
                bf16x8 a[4], bg[4], bu[4];
                #pragma unroll
                for (int m = 0; m < 4; ++m)
                    a[m] = *(const bf16x8*)(smA + swz(wr * 64 + m * 16 + (lane & 15), cb));
                #pragma unroll
                for (int n = 0; n < 4; ++n)
                    bg[n] = *(const bf16x8*)(smG + swz(wc * 64 + n * 16 + (lane & 15), cb));
                #pragma unroll
                for (int n = 0; n < 4; ++n)
                    bu[n] = *(const bf16x8*)(smU + swz(wc * 64 + n * 16 + (lane & 15), cb));
                #pragma unroll
                for (int m = 0; m < 4; ++m)
                    #pragma unroll
                    for (int n = 0; n < 4; ++n) {
                        accg[m][n] = __builtin_amdgcn_mfma_f32_16x16x32_bf16(a[m], bg[n], accg[m][n], 0, 0, 0);
                        accu[m][n] = __builtin_amdgcn_mfma_f32_16x16x32_bf16(a[m], bu[n], accu[m][n], 0, 0, 0);
                    }
            }
        }
    } else {
        // fallback: reg-staged, converts fp32 in-loop
        int row = tid >> 1, half = tid & 1;
        int wcolb = half * 64;
        int prc = row0 + (row < rows ? row : rows - 1);
        int tok = token_id[prc];
        const float* aSrc = x + (size_t)tok * Dd + half * 32;
        size_t wbase = ((size_t)e * Ff + (nt * BN + row)) * Dd + half * 32;
        for (int ks = 0; ks < Dd / BKK; ++ks) {
            __syncthreads();
            {
                const float4* s = (const float4*)(aSrc + ks * BKK);
                float4 f0 = s[0], f1 = s[1], f2 = s[2], f3 = s[3];
                float4 f4 = s[4], f5 = s[5], f6 = s[6], f7 = s[7];
                *(uint4*)(smA + swz(row, wcolb + 0))  = pack8(f0, f1);
                *(uint4*)(smA + swz(row, wcolb + 16)) = pack8(f2, f3);
                *(uint4*)(smA + swz(row, wcolb + 32)) = pack8(f4, f5);
                *(uint4*)(smA + swz(row, wcolb + 48)) = pack8(f6, f7);
            }
            {
                const float4* sg = (const float4*)(wgate_f + wbase + ks * BKK);
                float4 a0 = sg[0], a1 = sg[1], a2 = sg[2], a3 = sg[3];
                float4 a4 = sg[4], a5 = sg[5], a6 = sg[6], a7 = sg[7];
                *(uint4*)(smG + swz(row, wcolb + 0))  = pack8(a0, a1);
                *(uint4*)(smG + swz(row, wcolb + 16)) = pack8(a2, a3);
                *(uint4*)(smG + swz(row, wcolb + 32)) = pack8(a4, a5);
                *(uint4*)(smG + swz(row, wcolb + 48)) = pack8(a6, a7);
                const float4* su = (const float4*)(wup_f + wbase + ks * BKK);
                float4 b0 = su[0], b1 = su[1], b2 = su[2], b3 = su[3];
                float4 b4 = su[4], b5 = su[5], b6 = su[6], b7 = su[7];
                *(uint4*)(smU + swz(row, wcolb + 0))  = pack8(b0, b1);
                *(uint4*)(smU + swz(row, wcolb + 16)) = pack8(b2, b3);
                *(uint4*)(smU + swz(row, wcolb + 32)) = pack8(b4, b5);
                *(uint4*)(smU + swz(row, wcolb + 48)) = pack8(b6, b7);
            }
            __syncthreads();
            #pragma unroll
            for (int kk = 0; kk < 2; ++kk) {
                int cb = kk * 64 + ((lane >> 4) << 4);
                bf16x8 a[4], bg[4], bu[4];
                #pragma unroll
                for (int m = 0; m < 4; ++m)
                    a[m] = *(const bf16x8*)(smA + swz(wr * 64 + m * 16 + (lane & 15), cb));
                #pragma unroll
                for (int n = 0; n < 4; ++n)
                    bg[n] = *(const bf16x8*)(smG + swz(wc * 64 + n * 16 + (lane & 15), cb));
                #pragma unroll
                for (int n = 0; n < 4; ++n)
                    bu[n] = *(const bf16x8*)(smU + swz(wc * 64 + n * 16 + (lane & 15), cb));
                #pragma unroll
                for (int m = 0; m < 4; ++m)
                    #pragma unroll
                    for (int n = 0; n < 4; ++n) {
                        accg[m][n] = __builtin_amdgcn_mfma_f32_16x16x32_bf16(a[m], bg[n], accg[m][n], 0, 0, 0);
                        accu[m][n] = __builtin_amdgcn_mfma_f32_16x16x32_bf16(a[m], bu[n], accu[m][n], 0, 0, 0);
                    }
            }
        }
    }
    // epilogue: h = silu(g) * u -> bf16 into chunk-local hbuf
    int r0 = wr * 64 + ((lane >> 4) << 2);
    int c0 = nt * BN + wc * 64 + (lane & 15);
    #pragma unroll
    for (int m = 0; m < 4; ++m) {
        #pragma unroll
        for (int r = 0; r < 4; ++r) {
            int rr = r0 + m * 16 + r;
            if (rr < rows) {
                uint16_t* hp = hbuf + (size_t)(slot + rr) * Ff + c0;
                #pragma unroll
                for (int n = 0; n < 4; ++n) {
                    float g = accg[m][n][r];
                    float u = accu[m][n][r];
                    float h = g * u / (1.f + expf(-g));
                    hp[n * 16] = f2bf(h);
                }
            }
        }
    }
}

// ---------------- GEMM2: out += w * (h @ wd^T) ----------------
template<bool PRECONV>
__global__ __launch_bounds__(256) void gemm2_kernel(
    const uint16_t* __restrict__ hbuf,
    const float* __restrict__ wdown_f, const uint16_t* __restrict__ wdown_b,
    const int* __restrict__ seg_off, const int* __restrict__ tile_e,
    const int* __restrict__ tile_row0, const int* __restrict__ ntiles,
    const int* __restrict__ token_id, const float* __restrict__ pair_w,
    float* __restrict__ out, int tile0)
{
    int bx = blockIdx.x;
    int lt = bx / NT2, nt = bx - lt * NT2;
    int tidx = tile0 + lt;
    if (tidx >= *ntiles) return;
    int e = tile_e[tidx];
    int row0 = tile_row0[tidx];
    int rows = seg_off[e + 1] - row0; if (rows > BM) rows = BM;
    int slot = lt * BM;

    __shared__ uint4 ldsbuf[(BM * BKK * 2 * 2) / 16];
    char* smA = (char*)ldsbuf;
    char* smB = smA + BM * BKK * 2;

    int tid = threadIdx.x;
    int lane = tid & 63, wv = tid >> 6;
    int wr = wv >> 1, wc = wv & 1;

    f32x4 acc[4][4];
    f32x4 zero4 = {0.f, 0.f, 0.f, 0.f};
    #pragma unroll
    for (int m = 0; m < 4; ++m)
        #pragma unroll
        for (int n = 0; n < 4; ++n) acc[m][n] = zero4;

    if (PRECONV) {
        int lr = lane >> 3;
        int csw = ((lane & 7) ^ lr) * 8;
        const uint16_t* aB = hbuf + (size_t)(slot + wv * 32 + lr) * Ff + csw;
        const uint16_t* bB = wdown_b + ((size_t)e * Dd + nt * BN + wv * 32 + lr) * Ff + csw;
        char* aL = smA + wv * 4096;
        char* bL = smB + wv * 4096;

        for (int ks = 0; ks < Ff / BKK; ++ks) {   // 44 steps
            __syncthreads();
            #pragma unroll
            for (int i = 0; i < 4; ++i) {
                gload16(aB + (size_t)i * 8 * Ff + ks * BKK, aL + i * 1024);
                gload16(bB + (size_t)i * 8 * Ff + ks * BKK, bL + i * 1024);
            }
            __syncthreads();
            #pragma unroll
            for (int kk = 0; kk < 2; ++kk) {
                int cb = kk * 64 + ((lane >> 4) << 4);
                bf16x8 a[4], b[4];
                #pragma unroll
                for (int m = 0; m < 4; ++m)
                    a[m] = *(const bf16x8*)(smA + swz(wr * 64 + m * 16 + (lane & 15), cb));
                #pragma unroll
                for (int n = 0; n < 4; ++n)
                    b[n] = *(const bf16x8*)(smB + swz(wc * 64 + n * 16 + (lane & 15), cb));
                #pragma unroll
                for (int m = 0; m < 4; ++m)
                    #pragma unroll
                    for (int n = 0; n < 4; ++n)
                        acc[m][n] = __builtin_amdgcn_mfma_f32_16x16x32_bf16(a[m], b[n], acc[m][n], 0, 0, 0);
            }
        }
    } else {
        int row = tid >> 1, half = tid & 1;
        int wcolb = half * 64;
        const uint16_t* aSrc = hbuf + (size_t)(slot + row) * Ff + half * 32;
        size_t wbase = ((size_t)e * Dd + (nt * BN + row)) * Ff + half * 32;
        for (int ks = 0; ks < Ff / BKK; ++ks) {
            __syncthreads();
            {
                const uint4* s = (const uint4*)(aSrc + ks * BKK);
                uint4 v0 = s[0], v1 = s[1], v2 = s[2], v3 = s[3];
                *(uint4*)(smA + swz(row, wcolb + 0))  = v0;
                *(uint4*)(smA + swz(row, wcolb + 16)) = v1;
                *(uint4*)(smA + swz(row, wcolb + 32)) = v2;
                *(uint4*)(smA + swz(row, wcolb + 48)) = v3;
            }
            {
                const float4* sb = (const float4*)(wdown_f + wbase + ks * BKK);
                float4 a0 = sb[0], a1 = sb[1], a2 = sb[2], a3 = sb[3];
                float4 a4 = sb[4], a5 = sb[5], a6 = sb[6], a7 = sb[7];
                *(uint4*)(smB + swz(row, wcolb + 0))  = pack8(a0, a1);
                *(uint4*)(smB + swz(row, wcolb + 16)) = pack8(a2, a3);
                *(uint4*)(smB + swz(row, wcolb + 32)) = pack8(a4, a5);
                *(uint4*)(smB + swz(row, wcolb + 48)) = pack8(a6, a7);
            }
            __syncthreads();
            #pragma unroll
            for (int kk = 0; kk < 2; ++kk) {
                int cb = kk * 64 + ((lane >> 4) << 4);
                bf16x8 a[4], b[4];
                #pragma unroll
                for (int m = 0; m < 4; ++m)
                    a[m] = *(const bf16x8*)(smA + swz(wr * 64 + m * 16 + (lane & 15), cb));
                #pragma unroll
                for (int n = 0; n < 4; ++n)
                    b[n] = *(const bf16x8*)(smB + swz(wc * 64 + n * 16 + (lane & 15), cb));
                #pragma unroll
                for (int m = 0; m < 4; ++m)
                    #pragma unroll
                    for (int n = 0; n < 4; ++n)
                        acc[m][n] = __builtin_amdgcn_mfma_f32_16x16x32_bf16(a[m], b[n], acc[m][n], 0, 0, 0);
            }
        }
    }
    // epilogue: atomic combine into out (exactly 2 commutative adds/element -> deterministic)
    int r0 = wr * 64 + ((lane >> 4) << 2);
    int c0 = nt * BN + wc * 64 + (lane & 15);
    #pragma unroll
    for (int m = 0; m < 4; ++m) {
        #pragma unroll
        for (int r = 0; r < 4; ++r) {
            int rr = r0 + m * 16 + r;
            if (rr < rows) {
                int pr = row0 + rr;
                int tok = token_id[pr];
                float w = pair_w[pr];
                float* op = out + (size_t)tok * Dd + c0;
                #pragma unroll
                for (int n = 0; n < 4; ++n)
                    atomicAdd(op + n * 16, w * acc[m][n][r]);
            }
        }
    }
}

// ---------------- Host launch ----------------
extern "C" void kernel_launch(void* const* d_in, const int* in_sizes, int n_in,
                              void* d_out, int out_size, void* d_ws, size_t ws_size,
                              hipStream_t stream)
{
    const float* x     = (const float*)d_in[0];
    const float* gw    = (const float*)d_in[1];
    const float* wgate = (const float*)d_in[2];
    const float* wup   = (const float*)d_in[3];
    const float* wdown = (const float*)d_in[4];
    float* out = (float*)d_out;

    char* ws = (char*)d_ws;
    // Control region layout (270336 bytes total)
    float* usage_bank = (float*)(ws);             // 2048 B
    int*   counts     = (int*)(ws + 2048);        // 32 B
    int*   seg_off    = (int*)(ws + 2112);        // 36 B
    int*   cursor     = (int*)(ws + 2176);        // 32 B
    int*   ntiles     = (int*)(ws + 2240);        // 4 B
    int*   tile_e     = (int*)(ws + 4096);        // 1024 B
    int*   tile_row0  = (int*)(ws + 5120);        // 1024 B
    int*   tok_i      = (int*)(ws + 8192);        // 65536 B
    float* tok_w      = (float*)(ws + 73728);     // 65536 B
    int*   token_id   = (int*)(ws + 139264);      // 65536 B
    float* pair_w     = (float*)(ws + 204800);    // 65536 B
    const size_t CTRL  = 270336;
    const size_t TILEB = (size_t)BM * Ff * 2;         // 720,896 B per h-tile
    const size_t XgB   = (size_t)(Pp + BM) * Dd * 2;  // 33.8 MB (pad 128 rows for OOB-safe staging)
    const size_t WB3   = 3ull * Ee * Ff * Dd * 2;     // 138,412,032 B bf16 weights

    hipMemsetAsync(d_out, 0, (size_t)out_size * 4, stream);
    if (ws_size >= 4096) hipMemsetAsync(ws, 0, 4096, stream);
    if (ws_size < CTRL) return;   // cannot run at all; fail gracefully (no OOB)

    router_kernel<<<Tt / 4, 256, 0, stream>>>(x, gw, usage_bank, counts, tok_i, tok_w);
    scan_kernel<<<1, 64, 0, stream>>>(usage_bank, counts, seg_off, cursor,
                                      ntiles, tile_e, tile_row0, out + (out_size - 1));
    build_kernel<<<Tt / 256, 256, 0, stream>>>(tok_i, tok_w, cursor, token_id, pair_w);

    size_t avail = ws_size - CTRL;
    if (avail < TILEB) return;    // no room for even one h-tile; fail gracefully

    bool preconv = (avail >= XgB + WB3 + 32 * TILEB);
    uint16_t *Xg = nullptr, *wg_b = nullptr, *wu_b = nullptr, *wd_b = nullptr;
    uint16_t* hbuf;
    size_t hspace;
    if (preconv) {
        Xg   = (uint16_t*)(ws + CTRL);
        wg_b = (uint16_t*)(ws + CTRL + XgB);
        wu_b = wg_b + (size_t)Ee * Ff * Dd;
        wd_b = wu_b + (size_t)Ee * Ff * Dd;
        hbuf = (uint16_t*)(ws + CTRL + XgB + WB3);
        hspace = avail - XgB - WB3;
    } else {
        hbuf = (uint16_t*)(ws + CTRL);
        hspace = avail;
    }
    int Tc = (int)(hspace / TILEB);
    if (Tc > MAXT) Tc = MAXT;
    int nchunks = (MAXT + Tc - 1) / Tc;

    if (preconv) {
        long long n = (long long)Ee * Ff * Dd;   // 23,068,672 ; /2048 = 11264 blocks
        conv_kernel<<<11264, 256, 0, stream>>>(wgate, wg_b, n);
        conv_kernel<<<11264, 256, 0, stream>>>(wup,   wu_b, n);
        conv_kernel<<<11264, 256, 0, stream>>>(wdown, wd_b, n);
        gather_kernel<<<Pp / 4, 256, 0, stream>>>(x, token_id, Xg);
    }

    for (int c = 0; c < nchunks; ++c) {
        int tile0 = c * Tc;
        if (preconv) {
            gemm1_kernel<true><<<Tc * NT1, 256, 0, stream>>>(
                x, Xg, token_id, wgate, wup, wg_b, wu_b,
                seg_off, tile_e, tile_row0, ntiles, hbuf, tile0);
            gemm2_kernel<true><<<Tc * NT2, 256, 0, stream>>>(
                hbuf, wdown, wd_b, seg_off, tile_e, tile_row0, ntiles,
                token_id, pair_w, out, tile0);
        } else {
            gemm1_kernel<false><<<Tc * NT1, 256, 0, stream>>>(
                x, Xg, token_id, wgate, wup, wg_b, wu_b,
                seg_off, tile_e, tile_row0, ntiles, hbuf, tile0);
            gemm2_kernel<false><<<Tc * NT2, 256, 0, stream>>>(
                hbuf, wdown, wd_b, seg_off, tile_e, tile_row0, ntiles,
                token_id, pair_w, out, tile0);
        }
    }
}

// Round 4
// 797.947 us; speedup vs baseline: 1.4253x; 1.1690x over previous
//
#include <hip/hip_runtime.h>
#include <hip/hip_bf16.h>
#include <stdint.h>

// Problem dims
#define Dd 1024
#define Ee 8
#define Ff 2816
#define Tt 8192    // B*S tokens
#define Pp 16384   // Tt * K pairs

// GEMM tiling
#define BM 128
#define BKK 64
#define NT1 44             // F/64  (gemm1 N-tile = 64)
#define NT2 8              // D/128 (gemm2 N-tile = 128)
#define MAXT 136           // max M-tiles: Pp/BM + Ee (worst-case partial tiles)

using bf16x8 = __attribute__((ext_vector_type(8))) short;
using f32x4  = __attribute__((ext_vector_type(4))) float;

__device__ __forceinline__ uint16_t f2bf(float f) {
    union { float f; uint32_t u; } v; v.f = f;
    return (uint16_t)((v.u + 0x7fffu + ((v.u >> 16) & 1u)) >> 16);
}
__device__ __forceinline__ uint32_t pack2(float a, float b) {
    return (uint32_t)f2bf(a) | ((uint32_t)f2bf(b) << 16);
}
__device__ __forceinline__ uint4 pack8(float4 a, float4 b) {
    uint4 r; r.x = pack2(a.x, a.y); r.y = pack2(a.z, a.w);
    r.z = pack2(b.x, b.y); r.w = pack2(b.z, b.w); return r;
}
// XOR swizzle within a 128B LDS row (G4): spreads 16B slots across banks
__device__ __forceinline__ int swz(int row, int cb) {
    return row * 128 + (cb ^ ((row & 7) << 4));
}
// async global->LDS, 16B per lane; LDS dest is wave-uniform base (+lane*16 implicit)
__device__ __forceinline__ void gload16(const void* g, void* lds) {
    __builtin_amdgcn_global_load_lds(
        (const __attribute__((address_space(1))) uint32_t*)(uintptr_t)g,
        (__attribute__((address_space(3))) uint32_t*)(uintptr_t)lds,
        16, 0, 0);
}
// bijective XCD-chunk swizzle (m204): consecutive wgid -> same XCD
__device__ __forceinline__ int xcd_swz(int b, int nwg) {
    int xcd = b & 7, pos = b >> 3;
    int q = nwg >> 3, r = nwg & 7;
    return (xcd < r ? xcd * (q + 1) : r * (q + 1) + (xcd - r) * q) + pos;
}

// ---------------- Router: logits, top-2, softmax usage ----------------
__global__ __launch_bounds__(256) void router_kernel(
    const float* __restrict__ x, const float* __restrict__ gw,
    float* __restrict__ usage_bank, int* __restrict__ counts,
    int* __restrict__ tok_i, float* __restrict__ tok_w)
{
    __shared__ float us[Ee];
    int tid = threadIdx.x;
    if (tid < Ee) us[tid] = 0.f;
    __syncthreads();
    int wave = tid >> 6, lane = tid & 63;
    int t = blockIdx.x * 4 + wave;

    float xr[16];
    const float* xp = x + (size_t)t * Dd;
    #pragma unroll
    for (int j = 0; j < 16; ++j) xr[j] = xp[lane + 64 * j];

    float logits[Ee];
    #pragma unroll
    for (int e = 0; e < Ee; ++e) {
        const float* gp = gw + e * Dd;
        float s = 0.f;
        #pragma unroll
        for (int j = 0; j < 16; ++j) s += xr[j] * gp[lane + 64 * j];
        #pragma unroll
        for (int m = 1; m < 64; m <<= 1) s += __shfl_xor(s, m, 64);
        logits[e] = s;
    }
    // top-2 (strict > keeps lower index on ties, matching lax.top_k)
    float v1 = -1e30f, v2 = -1e30f; int i1 = 0, i2 = 0;
    #pragma unroll
    for (int e = 0; e < Ee; ++e) {
        float l = logits[e];
        if (l > v1) { v2 = v1; i2 = i1; v1 = l; i1 = e; }
        else if (l > v2) { v2 = l; i2 = e; }
    }
    float ex2 = expf(v2 - v1);
    float w1 = 1.f / (1.f + ex2);
    float w2 = ex2 * w1;
    // full softmax for expert usage (aux loss)
    float p[Ee]; float se = 0.f;
    #pragma unroll
    for (int e = 0; e < Ee; ++e) { p[e] = expf(logits[e] - v1); se += p[e]; }
    float inv = 1.f / se;
    if (lane == 0) {
        #pragma unroll
        for (int e = 0; e < Ee; ++e) atomicAdd(&us[e], p[e] * inv);
        atomicAdd(&counts[i1], 1);
        atomicAdd(&counts[i2], 1);
        tok_i[t * 2] = i1; tok_i[t * 2 + 1] = i2;
        tok_w[t * 2] = w1; tok_w[t * 2 + 1] = w2;
    }
    __syncthreads();
    if (tid < Ee) atomicAdd(&usage_bank[(blockIdx.x & 63) * Ee + tid], us[tid]);
}

// ---------------- Scan: aux loss + segment offsets + tile list ----------------
__global__ void scan_kernel(const float* __restrict__ usage_bank,
                            const int* __restrict__ counts,
                            int* __restrict__ seg_off, int* __restrict__ cursor,
                            int* __restrict__ ntiles, int* __restrict__ tile_e,
                            int* __restrict__ tile_row0, float* __restrict__ out_aux)
{
    int tid = threadIdx.x;
    __shared__ float us[Ee];
    if (tid < Ee) {
        float s = 0.f;
        for (int b = 0; b < 64; ++b) s += usage_bank[b * Ee + tid];
        us[tid] = s / (float)Tt;
    }
    __syncthreads();
    if (tid == 0) {
        float aux = 0.f;
        for (int e = 0; e < Ee; ++e) { float d = us[e] - 0.125f; aux += d * d; }
        *out_aux = aux;
        int off = 0;
        for (int e = 0; e < Ee; ++e) { seg_off[e] = off; cursor[e] = off; off += counts[e]; }
        seg_off[Ee] = off;  // == Pp
        int ti = 0;
        for (int e = 0; e < Ee; ++e) {
            int so = seg_off[e], cnt = counts[e];
            for (int r = 0; r < cnt; r += BM) { tile_e[ti] = e; tile_row0[ti] = so + r; ++ti; }
        }
        *ntiles = ti;   // <= MAXT
    }
}

// ---------------- Build per-expert pair lists ----------------
__global__ __launch_bounds__(256) void build_kernel(
    const int* __restrict__ tok_i, const float* __restrict__ tok_w,
    int* __restrict__ cursor, int* __restrict__ token_id, float* __restrict__ pair_w)
{
    int t = blockIdx.x * 256 + threadIdx.x;
    if (t >= Tt) return;
    int i1 = tok_i[t * 2], i2 = tok_i[t * 2 + 1];
    int s1 = atomicAdd(&cursor[i1], 1);
    token_id[s1] = t; pair_w[s1] = tok_w[t * 2];
    int s2 = atomicAdd(&cursor[i2], 1);
    token_id[s2] = t; pair_w[s2] = tok_w[t * 2 + 1];
}

// ---------------- Gather x rows -> bf16 Xg[pair, D] (4 rows/block) ----------------
__global__ __launch_bounds__(256) void gather_kernel(
    const float* __restrict__ x, const int* __restrict__ token_id,
    uint16_t* __restrict__ Xg)
{
    int wave = threadIdx.x >> 6, lane = threadIdx.x & 63;
    int r = blockIdx.x * 4 + wave;
    if (r >= Pp) return;
    int t = token_id[r];
    const float4* src = (const float4*)(x + (size_t)t * Dd) + lane * 4;
    float4 f0 = src[0], f1 = src[1], f2 = src[2], f3 = src[3];
    uint4* dst = (uint4*)(Xg + (size_t)r * Dd) + lane * 2;
    dst[0] = pack8(f0, f1);
    dst[1] = pack8(f2, f3);
}

// ---------------- fp32 -> bf16 weight conversion ----------------
__global__ __launch_bounds__(256) void conv_kernel(
    const float* __restrict__ src, uint16_t* __restrict__ dst, long long n)
{
    long long i = ((long long)blockIdx.x * 256 + threadIdx.x) * 8;
    if (i >= n) return;
    const float4* s = (const float4*)(src + i);
    float4 a = s[0], b = s[1];
    *(uint4*)(dst + i) = pack8(a, b);
}

// ---------------- GEMM1: gate+up, h = silu(g)*u ----------------
// Tile 128(M) x 64(h-cols); waves 2Mx2N, per-wave 64x32, acc = 64 VGPR (g)+(u).
// nt-major grid + XCD swizzle: consecutive blocks share the (e,nt) weight panel.
template<bool PRECONV>
__global__ __launch_bounds__(256) void gemm1_kernel(
    const float* __restrict__ x, const uint16_t* __restrict__ Xg,
    const int* __restrict__ token_id,
    const float* __restrict__ wgate_f, const float* __restrict__ wup_f,
    const uint16_t* __restrict__ wgate_b, const uint16_t* __restrict__ wup_b,
    const int* __restrict__ seg_off, const int* __restrict__ tile_e,
    const int* __restrict__ tile_row0, const int* __restrict__ ntiles,
    uint16_t* __restrict__ hbuf, int tile0, int Tc, int nwg)
{
    int wgid = xcd_swz(blockIdx.x, nwg);
    int nt = wgid / Tc, lt = wgid - nt * Tc;
    int tidx = tile0 + lt;
    if (tidx >= *ntiles) return;
    int e = tile_e[tidx];
    int row0 = tile_row0[tidx];
    int rows = seg_off[e + 1] - row0; if (rows > BM) rows = BM;
    int slot = lt * BM;  // chunk-local hbuf row base

    __shared__ uint4 ldsbuf[32768 / 16];   // A 16K | G 8K | U 8K
    char* smA = (char*)ldsbuf;
    char* smG = smA + 16384;
    char* smU = smA + 24576;

    int tid = threadIdx.x;
    int lane = tid & 63, wv = tid >> 6;
    int wr = wv >> 1, wc = wv & 1;

    f32x4 accg[4][2], accu[4][2];
    f32x4 zero4 = {0.f, 0.f, 0.f, 0.f};
    #pragma unroll
    for (int m = 0; m < 4; ++m)
        #pragma unroll
        for (int n = 0; n < 2; ++n) { accg[m][n] = zero4; accu[m][n] = zero4; }

    if (PRECONV) {
        // per-lane inverse-swizzled source addressing (rule #21: linear LDS dest)
        int lr = lane >> 3;                       // row within 8-row stripe
        int csw = ((lane & 7) ^ lr) * 8;          // source col chunk (elements)
        const uint16_t* aB = Xg + (size_t)(row0 + wv * 32 + lr) * Dd + csw;
        size_t wrow = (size_t)e * Ff + nt * 64 + wv * 16 + lr;
        const uint16_t* gB = wgate_b + wrow * Dd + csw;
        const uint16_t* uB = wup_b   + wrow * Dd + csw;
        char* aL = smA + wv * 4096;   // 32 rows per wave
        char* gL = smG + wv * 2048;   // 16 rows per wave
        char* uL = smU + wv * 2048;

        for (int ks = 0; ks < Dd / BKK; ++ks) {
            __syncthreads();
            #pragma unroll
            for (int i = 0; i < 4; ++i)
                gload16(aB + (size_t)i * 8 * Dd + ks * BKK, aL + i * 1024);
            #pragma unroll
            for (int i = 0; i < 2; ++i) {
                gload16(gB + (size_t)i * 8 * Dd + ks * BKK, gL + i * 1024);
                gload16(uB + (size_t)i * 8 * Dd + ks * BKK, uL + i * 1024);
            }
            __syncthreads();
            #pragma unroll
            for (int kk = 0; kk < 2; ++kk) {
                int cb = kk * 64 + ((lane >> 4) << 4);
                bf16x8 a[4], bg[2], bu[2];
                #pragma unroll
                for (int m = 0; m < 4; ++m)
                    a[m] = *(const bf16x8*)(smA + swz(wr * 64 + m * 16 + (lane & 15), cb));
                #pragma unroll
                for (int n = 0; n < 2; ++n) {
                    bg[n] = *(const bf16x8*)(smG + swz(wc * 32 + n * 16 + (lane & 15), cb));
                    bu[n] = *(const bf16x8*)(smU + swz(wc * 32 + n * 16 + (lane & 15), cb));
                }
                #pragma unroll
                for (int m = 0; m < 4; ++m)
                    #pragma unroll
                    for (int n = 0; n < 2; ++n) {
                        accg[m][n] = __builtin_amdgcn_mfma_f32_16x16x32_bf16(a[m], bg[n], accg[m][n], 0, 0, 0);
                        accu[m][n] = __builtin_amdgcn_mfma_f32_16x16x32_bf16(a[m], bu[n], accu[m][n], 0, 0, 0);
                    }
            }
        }
    } else {
        // fallback: reg-staged from fp32 sources (performance-irrelevant path)
        for (int ks = 0; ks < Dd / BKK; ++ks) {
            __syncthreads();
            for (int idx = tid; idx < 1024; idx += 256) {       // A: 128 rows x 8 chunks
                int row = idx >> 3, ch = idx & 7;
                int prc = row0 + (row < rows ? row : rows - 1);
                int tok = token_id[prc];
                const float* s = x + (size_t)tok * Dd + ks * BKK + ch * 8;
                *(uint4*)(smA + swz(row, ch * 16)) =
                    pack8(*(const float4*)s, *(const float4*)(s + 4));
            }
            for (int idx = tid; idx < 512; idx += 256) {        // G,U: 64 rows x 8 chunks
                int row = idx >> 3, ch = idx & 7;
                size_t wrow = ((size_t)e * Ff + nt * 64 + row) * Dd + ks * BKK + ch * 8;
                const float* sg = wgate_f + wrow;
                *(uint4*)(smG + swz(row, ch * 16)) =
                    pack8(*(const float4*)sg, *(const float4*)(sg + 4));
                const float* su = wup_f + wrow;
                *(uint4*)(smU + swz(row, ch * 16)) =
                    pack8(*(const float4*)su, *(const float4*)(su + 4));
            }
            __syncthreads();
            #pragma unroll
            for (int kk = 0; kk < 2; ++kk) {
                int cb = kk * 64 + ((lane >> 4) << 4);
                bf16x8 a[4], bg[2], bu[2];
                #pragma unroll
                for (int m = 0; m < 4; ++m)
                    a[m] = *(const bf16x8*)(smA + swz(wr * 64 + m * 16 + (lane & 15), cb));
                #pragma unroll
                for (int n = 0; n < 2; ++n) {
                    bg[n] = *(const bf16x8*)(smG + swz(wc * 32 + n * 16 + (lane & 15), cb));
                    bu[n] = *(const bf16x8*)(smU + swz(wc * 32 + n * 16 + (lane & 15), cb));
                }
                #pragma unroll
                for (int m = 0; m < 4; ++m)
                    #pragma unroll
                    for (int n = 0; n < 2; ++n) {
                        accg[m][n] = __builtin_amdgcn_mfma_f32_16x16x32_bf16(a[m], bg[n], accg[m][n], 0, 0, 0);
                        accu[m][n] = __builtin_amdgcn_mfma_f32_16x16x32_bf16(a[m], bu[n], accu[m][n], 0, 0, 0);
                    }
            }
        }
    }
    // epilogue: h = silu(g) * u -> bf16 into chunk-local hbuf
    int r0 = wr * 64 + ((lane >> 4) << 2);
    int c0 = nt * 64 + wc * 32 + (lane & 15);
    #pragma unroll
    for (int m = 0; m < 4; ++m) {
        #pragma unroll
        for (int r = 0; r < 4; ++r) {
            int rr = r0 + m * 16 + r;
            if (rr < rows) {
                uint16_t* hp = hbuf + (size_t)(slot + rr) * Ff + c0;
                #pragma unroll
                for (int n = 0; n < 2; ++n) {
                    float g = accg[m][n][r];
                    float u = accu[m][n][r];
                    float h = g * u / (1.f + expf(-g));
                    hp[n * 16] = f2bf(h);
                }
            }
        }
    }
}

// ---------------- GEMM2: out += w * (h @ wd^T) ----------------
template<bool PRECONV>
__global__ __launch_bounds__(256) void gemm2_kernel(
    const uint16_t* __restrict__ hbuf,
    const float* __restrict__ wdown_f, const uint16_t* __restrict__ wdown_b,
    const int* __restrict__ seg_off, const int* __restrict__ tile_e,
    const int* __restrict__ tile_row0, const int* __restrict__ ntiles,
    const int* __restrict__ token_id, const float* __restrict__ pair_w,
    float* __restrict__ out, int tile0, int Tc, int nwg)
{
    int wgid = xcd_swz(blockIdx.x, nwg);
    int nt = wgid / Tc, lt = wgid - nt * Tc;
    int tidx = tile0 + lt;
    if (tidx >= *ntiles) return;
    int e = tile_e[tidx];
    int row0 = tile_row0[tidx];
    int rows = seg_off[e + 1] - row0; if (rows > BM) rows = BM;
    int slot = lt * BM;

    __shared__ uint4 ldsbuf[32768 / 16];   // A 16K | B 16K
    char* smA = (char*)ldsbuf;
    char* smB = smA + 16384;

    int tid = threadIdx.x;
    int lane = tid & 63, wv = tid >> 6;
    int wr = wv >> 1, wc = wv & 1;

    f32x4 acc[4][4];
    f32x4 zero4 = {0.f, 0.f, 0.f, 0.f};
    #pragma unroll
    for (int m = 0; m < 4; ++m)
        #pragma unroll
        for (int n = 0; n < 4; ++n) acc[m][n] = zero4;

    if (PRECONV) {
        int lr = lane >> 3;
        int csw = ((lane & 7) ^ lr) * 8;
        const uint16_t* aB = hbuf + (size_t)(slot + wv * 32 + lr) * Ff + csw;
        const uint16_t* bB = wdown_b + ((size_t)e * Dd + nt * 128 + wv * 32 + lr) * Ff + csw;
        char* aL = smA + wv * 4096;
        char* bL = smB + wv * 4096;

        for (int ks = 0; ks < Ff / BKK; ++ks) {   // 44 steps
            __syncthreads();
            #pragma unroll
            for (int i = 0; i < 4; ++i) {
                gload16(aB + (size_t)i * 8 * Ff + ks * BKK, aL + i * 1024);
                gload16(bB + (size_t)i * 8 * Ff + ks * BKK, bL + i * 1024);
            }
            __syncthreads();
            #pragma unroll
            for (int kk = 0; kk < 2; ++kk) {
                int cb = kk * 64 + ((lane >> 4) << 4);
                bf16x8 a[4], b[4];
                #pragma unroll
                for (int m = 0; m < 4; ++m)
                    a[m] = *(const bf16x8*)(smA + swz(wr * 64 + m * 16 + (lane & 15), cb));
                #pragma unroll
                for (int n = 0; n < 4; ++n)
                    b[n] = *(const bf16x8*)(smB + swz(wc * 64 + n * 16 + (lane & 15), cb));
                #pragma unroll
                for (int m = 0; m < 4; ++m)
                    #pragma unroll
                    for (int n = 0; n < 4; ++n)
                        acc[m][n] = __builtin_amdgcn_mfma_f32_16x16x32_bf16(a[m], b[n], acc[m][n], 0, 0, 0);
            }
        }
    } else {
        for (int ks = 0; ks < Ff / BKK; ++ks) {
            __syncthreads();
            for (int idx = tid; idx < 1024; idx += 256) {   // A: 128 rows x 8 chunks (bf16)
                int row = idx >> 3, ch = idx & 7;
                const uint16_t* s = hbuf + (size_t)(slot + row) * Ff + ks * BKK + ch * 8;
                *(uint4*)(smA + swz(row, ch * 16)) = *(const uint4*)s;
            }
            for (int idx = tid; idx < 1024; idx += 256) {   // B: 128 rows x 8 chunks (fp32)
                int row = idx >> 3, ch = idx & 7;
                const float* s = wdown_f + ((size_t)e * Dd + nt * 128 + row) * Ff + ks * BKK + ch * 8;
                *(uint4*)(smB + swz(row, ch * 16)) =
                    pack8(*(const float4*)s, *(const float4*)(s + 4));
            }
            __syncthreads();
            #pragma unroll
            for (int kk = 0; kk < 2; ++kk) {
                int cb = kk * 64 + ((lane >> 4) << 4);
                bf16x8 a[4], b[4];
                #pragma unroll
                for (int m = 0; m < 4; ++m)
                    a[m] = *(const bf16x8*)(smA + swz(wr * 64 + m * 16 + (lane & 15), cb));
                #pragma unroll
                for (int n = 0; n < 4; ++n)
                    b[n] = *(const bf16x8*)(smB + swz(wc * 64 + n * 16 + (lane & 15), cb));
                #pragma unroll
                for (int m = 0; m < 4; ++m)
                    #pragma unroll
                    for (int n = 0; n < 4; ++n)
                        acc[m][n] = __builtin_amdgcn_mfma_f32_16x16x32_bf16(a[m], b[n], acc[m][n], 0, 0, 0);
            }
        }
    }
    // epilogue: atomic combine into out (exactly 2 commutative adds/element -> deterministic)
    int r0 = wr * 64 + ((lane >> 4) << 2);
    int c0 = nt * 128 + wc * 64 + (lane & 15);
    #pragma unroll
    for (int m = 0; m < 4; ++m) {
        #pragma unroll
        for (int r = 0; r < 4; ++r) {
            int rr = r0 + m * 16 + r;
            if (rr < rows) {
                int pr = row0 + rr;
                int tok = token_id[pr];
                float w = pair_w[pr];
                float* op = out + (size_t)tok * Dd + c0;
                #pragma unroll
                for (int n = 0; n < 4; ++n)
                    atomicAdd(op + n * 16, w * acc[m][n][r]);
            }
        }
    }
}

// ---------------- Host launch ----------------
extern "C" void kernel_launch(void* const* d_in, const int* in_sizes, int n_in,
                              void* d_out, int out_size, void* d_ws, size_t ws_size,
                              hipStream_t stream)
{
    const float* x     = (const float*)d_in[0];
    const float* gw    = (const float*)d_in[1];
    const float* wgate = (const float*)d_in[2];
    const float* wup   = (const float*)d_in[3];
    const float* wdown = (const float*)d_in[4];
    float* out = (float*)d_out;

    char* ws = (char*)d_ws;
    // Control region layout (270336 bytes total)
    float* usage_bank = (float*)(ws);             // 2048 B
    int*   counts     = (int*)(ws + 2048);        // 32 B
    int*   seg_off    = (int*)(ws + 2112);        // 36 B
    int*   cursor     = (int*)(ws + 2176);        // 32 B
    int*   ntiles     = (int*)(ws + 2240);        // 4 B
    int*   tile_e     = (int*)(ws + 4096);        // 1024 B
    int*   tile_row0  = (int*)(ws + 5120);        // 1024 B
    int*   tok_i      = (int*)(ws + 8192);        // 65536 B
    float* tok_w      = (float*)(ws + 73728);     // 65536 B
    int*   token_id   = (int*)(ws + 139264);      // 65536 B
    float* pair_w     = (float*)(ws + 204800);    // 65536 B
    const size_t CTRL  = 270336;
    const size_t TILEB = (size_t)BM * Ff * 2;         // 720,896 B per h-tile
    const size_t XgB   = (size_t)(Pp + BM) * Dd * 2;  // 33.8 MB (pad 128 rows for OOB-safe staging)
    const size_t WB3   = 3ull * Ee * Ff * Dd * 2;     // 138,412,032 B bf16 weights

    hipMemsetAsync(d_out, 0, (size_t)out_size * 4, stream);
    if (ws_size >= 4096) hipMemsetAsync(ws, 0, 4096, stream);
    if (ws_size < CTRL) return;   // cannot run at all; fail gracefully (no OOB)

    router_kernel<<<Tt / 4, 256, 0, stream>>>(x, gw, usage_bank, counts, tok_i, tok_w);
    scan_kernel<<<1, 64, 0, stream>>>(usage_bank, counts, seg_off, cursor,
                                      ntiles, tile_e, tile_row0, out + (out_size - 1));
    build_kernel<<<Tt / 256, 256, 0, stream>>>(tok_i, tok_w, cursor, token_id, pair_w);

    size_t avail = ws_size - CTRL;
    if (avail < TILEB) return;    // no room for even one h-tile; fail gracefully

    bool preconv = (avail >= XgB + WB3 + 32 * TILEB);
    uint16_t *Xg = nullptr, *wg_b = nullptr, *wu_b = nullptr, *wd_b = nullptr;
    uint16_t* hbuf;
    size_t hspace;
    if (preconv) {
        Xg   = (uint16_t*)(ws + CTRL);
        wg_b = (uint16_t*)(ws + CTRL + XgB);
        wu_b = wg_b + (size_t)Ee * Ff * Dd;
        wd_b = wu_b + (size_t)Ee * Ff * Dd;
        hbuf = (uint16_t*)(ws + CTRL + XgB + WB3);
        hspace = avail - XgB - WB3;
    } else {
        hbuf = (uint16_t*)(ws + CTRL);
        hspace = avail;
    }
    int Tc = (int)(hspace / TILEB);
    if (Tc > MAXT) Tc = MAXT;
    int nchunks = (MAXT + Tc - 1) / Tc;

    if (preconv) {
        long long n = (long long)Ee * Ff * Dd;   // 23,068,672 ; /2048 = 11264 blocks
        conv_kernel<<<11264, 256, 0, stream>>>(wgate, wg_b, n);
        conv_kernel<<<11264, 256, 0, stream>>>(wup,   wu_b, n);
        conv_kernel<<<11264, 256, 0, stream>>>(wdown, wd_b, n);
        gather_kernel<<<Pp / 4, 256, 0, stream>>>(x, token_id, Xg);
    }

    int nwg1 = Tc * NT1;
    int nwg2 = Tc * NT2;
    for (int c = 0; c < nchunks; ++c) {
        int tile0 = c * Tc;
        if (preconv) {
            gemm1_kernel<true><<<nwg1, 256, 0, stream>>>(
                x, Xg, token_id, wgate, wup, wg_b, wu_b,
                seg_off, tile_e, tile_row0, ntiles, hbuf, tile0, Tc, nwg1);
            gemm2_kernel<true><<<nwg2, 256, 0, stream>>>(
                hbuf, wdown, wd_b, seg_off, tile_e, tile_row0, ntiles,
                token_id, pair_w, out, tile0, Tc, nwg2);
        } else {
            gemm1_kernel<false><<<nwg1, 256, 0, stream>>>(
                x, Xg, token_id, wgate, wup, wg_b, wu_b,
                seg_off, tile_e, tile_row0, ntiles, hbuf, tile0, Tc, nwg1);
            gemm2_kernel<false><<<nwg2, 256, 0, stream>>>(
                hbuf, wdown, wd_b, seg_off, tile_e, tile_row0, ntiles,
                token_id, pair_w, out, tile0, Tc, nwg2);
        }
    }
}

// Round 5
// 769.760 us; speedup vs baseline: 1.4775x; 1.0366x over previous
//
#include <hip/hip_runtime.h>
#include <hip/hip_bf16.h>
#include <stdint.h>

// Problem dims
#define Dd 1024
#define Ee 8
#define Ff 2816
#define Tt 8192    // B*S tokens
#define Pp 16384   // Tt * K pairs

#define BMT 256            // M tile
#define MAXT 72            // max M-tiles: Pp/256 + Ee

using bf16x8 = __attribute__((ext_vector_type(8))) short;
using f32x4  = __attribute__((ext_vector_type(4))) float;

__device__ __forceinline__ uint16_t f2bf(float f) {
    union { float f; uint32_t u; } v; v.f = f;
    return (uint16_t)((v.u + 0x7fffu + ((v.u >> 16) & 1u)) >> 16);
}
__device__ __forceinline__ uint32_t pack2(float a, float b) {
    return (uint32_t)f2bf(a) | ((uint32_t)f2bf(b) << 16);
}
__device__ __forceinline__ uint4 pack8(float4 a, float4 b) {
    uint4 r; r.x = pack2(a.x, a.y); r.y = pack2(a.z, a.w);
    r.z = pack2(b.x, b.y); r.w = pack2(b.z, b.w); return r;
}
// XOR swizzle within a 128B LDS row (G4)
__device__ __forceinline__ int swz(int row, int cb) {
    return row * 128 + (cb ^ ((row & 7) << 4));
}
__device__ __forceinline__ void gload16(const void* g, void* lds) {
    __builtin_amdgcn_global_load_lds(
        (const __attribute__((address_space(1))) uint32_t*)(uintptr_t)g,
        (__attribute__((address_space(3))) uint32_t*)(uintptr_t)lds,
        16, 0, 0);
}
__device__ __forceinline__ int xcd_swz(int b, int nwg) {
    int xcd = b & 7, pos = b >> 3;
    int q = nwg >> 3, r = nwg & 7;
    return (xcd < r ? xcd * (q + 1) : r * (q + 1) + (xcd - r) * q) + pos;
}

// ---------------- Router ----------------
__global__ __launch_bounds__(256) void router_kernel(
    const float* __restrict__ x, const float* __restrict__ gw,
    float* __restrict__ usage_bank, int* __restrict__ counts,
    int* __restrict__ tok_i, float* __restrict__ tok_w)
{
    __shared__ float us[Ee];
    int tid = threadIdx.x;
    if (tid < Ee) us[tid] = 0.f;
    __syncthreads();
    int wave = tid >> 6, lane = tid & 63;
    int t = blockIdx.x * 4 + wave;

    float xr[16];
    const float* xp = x + (size_t)t * Dd;
    #pragma unroll
    for (int j = 0; j < 16; ++j) xr[j] = xp[lane + 64 * j];

    float logits[Ee];
    #pragma unroll
    for (int e = 0; e < Ee; ++e) {
        const float* gp = gw + e * Dd;
        float s = 0.f;
        #pragma unroll
        for (int j = 0; j < 16; ++j) s += xr[j] * gp[lane + 64 * j];
        #pragma unroll
        for (int m = 1; m < 64; m <<= 1) s += __shfl_xor(s, m, 64);
        logits[e] = s;
    }
    float v1 = -1e30f, v2 = -1e30f; int i1 = 0, i2 = 0;
    #pragma unroll
    for (int e = 0; e < Ee; ++e) {
        float l = logits[e];
        if (l > v1) { v2 = v1; i2 = i1; v1 = l; i1 = e; }
        else if (l > v2) { v2 = l; i2 = e; }
    }
    float ex2 = expf(v2 - v1);
    float w1 = 1.f / (1.f + ex2);
    float w2 = ex2 * w1;
    float p[Ee]; float se = 0.f;
    #pragma unroll
    for (int e = 0; e < Ee; ++e) { p[e] = expf(logits[e] - v1); se += p[e]; }
    float inv = 1.f / se;
    if (lane == 0) {
        #pragma unroll
        for (int e = 0; e < Ee; ++e) atomicAdd(&us[e], p[e] * inv);
        atomicAdd(&counts[i1], 1);
        atomicAdd(&counts[i2], 1);
        tok_i[t * 2] = i1; tok_i[t * 2 + 1] = i2;
        tok_w[t * 2] = w1; tok_w[t * 2 + 1] = w2;
    }
    __syncthreads();
    if (tid < Ee) atomicAdd(&usage_bank[(blockIdx.x & 63) * Ee + tid], us[tid]);
}

// ---------------- Scan: aux + offsets + tile list ----------------
__global__ void scan_kernel(const float* __restrict__ usage_bank,
                            const int* __restrict__ counts,
                            int* __restrict__ seg_off, int* __restrict__ cursor,
                            int* __restrict__ ntiles, int* __restrict__ tile_e,
                            int* __restrict__ tile_row0, float* __restrict__ out_aux)
{
    int tid = threadIdx.x;
    __shared__ float us[Ee];
    if (tid < Ee) {
        float s = 0.f;
        for (int b = 0; b < 64; ++b) s += usage_bank[b * Ee + tid];
        us[tid] = s / (float)Tt;
    }
    __syncthreads();
    if (tid == 0) {
        float aux = 0.f;
        for (int e = 0; e < Ee; ++e) { float d = us[e] - 0.125f; aux += d * d; }
        *out_aux = aux;
        int off = 0;
        for (int e = 0; e < Ee; ++e) { seg_off[e] = off; cursor[e] = off; off += counts[e]; }
        seg_off[Ee] = off;
        int ti = 0;
        for (int e = 0; e < Ee; ++e) {
            int so = seg_off[e], cnt = counts[e];
            for (int r = 0; r < cnt; r += BMT) { tile_e[ti] = e; tile_row0[ti] = so + r; ++ti; }
        }
        *ntiles = ti;   // <= MAXT
    }
}

// ---------------- Build pair lists (+ token->slot map) ----------------
__global__ __launch_bounds__(256) void build_kernel(
    const int* __restrict__ tok_i, const float* __restrict__ tok_w,
    int* __restrict__ cursor, int* __restrict__ token_id, float* __restrict__ pair_w,
    int* __restrict__ pos)
{
    int t = blockIdx.x * 256 + threadIdx.x;
    if (t >= Tt) return;
    int i1 = tok_i[t * 2], i2 = tok_i[t * 2 + 1];
    int s1 = atomicAdd(&cursor[i1], 1);
    token_id[s1] = t; pair_w[s1] = tok_w[t * 2];     pos[t * 2] = s1;
    int s2 = atomicAdd(&cursor[i2], 1);
    token_id[s2] = t; pair_w[s2] = tok_w[t * 2 + 1]; pos[t * 2 + 1] = s2;
}

// ---------------- Gather x rows -> bf16 Xg[pair, D] ----------------
__global__ __launch_bounds__(256) void gather_kernel(
    const float* __restrict__ x, const int* __restrict__ token_id,
    uint16_t* __restrict__ Xg)
{
    int wave = threadIdx.x >> 6, lane = threadIdx.x & 63;
    int r = blockIdx.x * 4 + wave;
    if (r >= Pp) return;
    int t = token_id[r];
    const float4* src = (const float4*)(x + (size_t)t * Dd) + lane * 4;
    float4 f0 = src[0], f1 = src[1], f2 = src[2], f3 = src[3];
    uint4* dst = (uint4*)(Xg + (size_t)r * Dd) + lane * 2;
    dst[0] = pack8(f0, f1);
    dst[1] = pack8(f2, f3);
}

// ---------------- fp32 -> bf16 plain conversion (w_down) ----------------
__global__ __launch_bounds__(256) void conv_kernel(
    const float* __restrict__ src, uint16_t* __restrict__ dst, long long n)
{
    long long i = ((long long)blockIdx.x * 256 + threadIdx.x) * 8;
    if (i >= n) return;
    const float4* s = (const float4*)(src + i);
    float4 a = s[0], b = s[1];
    *(uint4*)(dst + i) = pack8(a, b);
}

// ---------------- gate/up -> interleaved bf16 W1b ----------------
// W1b[e] has 5632 rows: row (f>>4)*32 + (f&15) = gate f ; +16 = up f.
__global__ __launch_bounds__(256) void conv_w1_kernel(
    const float* __restrict__ gsrc, const float* __restrict__ usrc,
    uint16_t* __restrict__ dst)
{
    long long i = ((long long)blockIdx.x * 256 + threadIdx.x) * 8;
    if (i >= (long long)Ee * Ff * Dd) return;
    int d = (int)(i & (Dd - 1));
    long long row = i >> 10;            // e*Ff + f
    int e = (int)(row / Ff), f = (int)(row - (long long)e * Ff);
    size_t rg = (size_t)e * 5632 + (size_t)(f >> 4) * 32 + (f & 15);
    const float4* sg = (const float4*)(gsrc + i);
    *(uint4*)(dst + rg * 1024 + d) = pack8(sg[0], sg[1]);
    const float4* su = (const float4*)(usrc + i);
    *(uint4*)(dst + (rg + 16) * 1024 + d) = pack8(su[0], su[1]);
}

// ---------------- Pipelined GEMM template ----------------
// BM=256, BK=64, 512 threads (8 waves). Double-buffered LDS, counted vmcnt.
// MODE 0: gemm1 (A=Xg, B=W1b interleaved, BN=256, epilogue silu*u -> hbuf bf16)
// MODE 1: gemm2 store (A=hbuf, B=wd_b, BN=128, epilogue P[pr] = y row, fp32)
// MODE 2: gemm2 atomic (epilogue atomicAdd into out)
#define LGKM0 asm volatile("s_waitcnt lgkmcnt(0)" ::: "memory")
#define SCHED0 __builtin_amdgcn_sched_barrier(0)

template<int NKT, int BN, int MODE>
__global__ __launch_bounds__(512, 2) void gemm_pipe(
    const uint16_t* __restrict__ Abase, const uint16_t* __restrict__ Bbase,
    const int* __restrict__ seg_off, const int* __restrict__ tile_e,
    const int* __restrict__ tile_row0, const int* __restrict__ ntiles,
    const int* __restrict__ token_id, const float* __restrict__ pair_w,
    uint16_t* __restrict__ hbuf, float* __restrict__ Pbuf, float* __restrict__ out,
    int tile0, int Tc, int nwg)
{
    constexpr int NW = BN / 64;            // waves along N
    constexpr int MW = 8 / NW;             // waves along M
    constexpr int MF = 256 / (MW * 16);    // m-frags per wave
    constexpr int LDA = (MODE == 0) ? Dd : Ff;
    constexpr int LDB = (MODE == 0) ? Dd : Ff;
    constexpr int BROUNDS = BN / 64;
    constexpr int BUFB = 32768 + BN * 128;

    int wgid = xcd_swz(blockIdx.x, nwg);
    int nt = wgid / Tc, lt = wgid - nt * Tc;
    int tidx = tile0 + lt;
    if (tidx >= *ntiles) return;
    int e = tile_e[tidx];
    int row0 = tile_row0[tidx];
    int rows = seg_off[e + 1] - row0; if (rows > BMT) rows = BMT;
    int slot = lt * BMT;

    __shared__ uint4 lds4[(2 * BUFB) / 16];
    char* lds = (char*)lds4;

    int tid = threadIdx.x, lane = tid & 63, wv = tid >> 6;
    int wr = wv / NW, wc = wv % NW;

    // per-lane inverse-swizzled staging sources (rule #21: LDS dest linear)
    int srow = wv * 8 + (lane >> 3);
    int csw = ((lane & 7) ^ (lane >> 3)) * 8;
    const uint16_t* aP;
    const uint16_t* bP;
    if constexpr (MODE == 0) {
        aP = Abase + (size_t)(row0 + srow) * LDA + csw;
        bP = Bbase + ((size_t)e * 5632 + nt * (size_t)BN + srow) * LDB + csw;
    } else {
        aP = Abase + (size_t)(slot + srow) * LDA + csw;
        bP = Bbase + ((size_t)e * Dd + nt * (size_t)BN + srow) * LDB + csw;
    }

    auto STAGE = [&](int kt, int c) {
        char* base = lds + c * BUFB;
        #pragma unroll
        for (int i = 0; i < 4; ++i)
            gload16(aP + (size_t)(i * 64) * LDA + kt * 64, base + i * 8192 + wv * 1024);
        #pragma unroll
        for (int i = 0; i < BROUNDS; ++i)
            gload16(bP + (size_t)(i * 64) * LDB + kt * 64, base + 32768 + i * 8192 + wv * 1024);
    };

    f32x4 acc[MF][4];
    f32x4 zero4 = {0.f, 0.f, 0.f, 0.f};
    #pragma unroll
    for (int m = 0; m < MF; ++m)
        #pragma unroll
        for (int n = 0; n < 4; ++n) acc[m][n] = zero4;

    STAGE(0, 0);
    STAGE(1, 1);
    if constexpr (BN == 256) asm volatile("s_waitcnt vmcnt(8)" ::: "memory");
    else                     asm volatile("s_waitcnt vmcnt(6)" ::: "memory");
    __builtin_amdgcn_s_barrier();
    SCHED0;

    #pragma unroll 1
    for (int t = 0; t < NKT; ++t) {
        int c = t & 1;
        char* smA = lds + c * BUFB;
        char* smB = smA + 32768;
        bf16x8 a[2][MF], b[2][4];
        #pragma unroll
        for (int kk = 0; kk < 2; ++kk) {
            int cb = kk * 64 + ((lane >> 4) << 4);
            #pragma unroll
            for (int m = 0; m < MF; ++m)
                a[kk][m] = *(const bf16x8*)(smA + swz(wr * (MF * 16) + m * 16 + (lane & 15), cb));
            #pragma unroll
            for (int n = 0; n < 4; ++n)
                b[kk][n] = *(const bf16x8*)(smB + swz(wc * 64 + n * 16 + (lane & 15), cb));
        }
        LGKM0;           // this wave's frags are in regs
        SCHED0;
        __builtin_amdgcn_s_barrier();   // all waves done reading buf c
        SCHED0;
        if (t + 2 < NKT) STAGE(t + 2, c);   // safe: buf c free; lands before iter t+2
        __builtin_amdgcn_s_setprio(1);
        #pragma unroll
        for (int kk = 0; kk < 2; ++kk)
            #pragma unroll
            for (int m = 0; m < MF; ++m)
                #pragma unroll
                for (int n = 0; n < 4; ++n)
                    acc[m][n] = __builtin_amdgcn_mfma_f32_16x16x32_bf16(a[kk][m], b[kk][n], acc[m][n], 0, 0, 0);
        __builtin_amdgcn_s_setprio(0);
        SCHED0;
        if (t + 2 < NKT) {   // counted: tile t+1 done, t+2 still in flight
            if constexpr (BN == 256) asm volatile("s_waitcnt vmcnt(8)" ::: "memory");
            else                     asm volatile("s_waitcnt vmcnt(6)" ::: "memory");
        } else {
            asm volatile("s_waitcnt vmcnt(0)" ::: "memory");   // tail drain
        }
        __builtin_amdgcn_s_barrier();
        SCHED0;
    }

    if constexpr (MODE == 0) {
        // n-frags alternate gate/up: h = silu(g)*u, 2 h-cols per m-frag
        int hc = nt * 128 + wc * 32 + (lane & 15);
        #pragma unroll
        for (int m = 0; m < MF; ++m) {
            #pragma unroll
            for (int g = 0; g < 4; ++g) {
                int rr = wr * 128 + m * 16 + (lane >> 4) * 4 + g;
                if (rr < rows) {
                    uint16_t* hp = hbuf + (size_t)(slot + rr) * Ff + hc;
                    float g0 = acc[m][0][g], u0 = acc[m][1][g];
                    hp[0]  = f2bf(g0 * u0 / (1.f + expf(-g0)));
                    float g1 = acc[m][2][g], u1 = acc[m][3][g];
                    hp[16] = f2bf(g1 * u1 / (1.f + expf(-g1)));
                }
            }
        }
    } else if constexpr (MODE == 1) {
        int col = nt * 128 + wc * 64 + (lane & 15);
        #pragma unroll
        for (int m = 0; m < MF; ++m) {
            #pragma unroll
            for (int g = 0; g < 4; ++g) {
                int rr = wr * 64 + m * 16 + (lane >> 4) * 4 + g;
                if (rr < rows) {
                    float* pp = Pbuf + (size_t)(row0 + rr) * Dd + col;
                    pp[0]  = acc[m][0][g];
                    pp[16] = acc[m][1][g];
                    pp[32] = acc[m][2][g];
                    pp[48] = acc[m][3][g];
                }
            }
        }
    } else {
        int col = nt * 128 + wc * 64 + (lane & 15);
        #pragma unroll
        for (int m = 0; m < MF; ++m) {
            #pragma unroll
            for (int g = 0; g < 4; ++g) {
                int rr = wr * 64 + m * 16 + (lane >> 4) * 4 + g;
                if (rr < rows) {
                    int pr = row0 + rr;
                    int tok = token_id[pr];
                    float w = pair_w[pr];
                    float* op = out + (size_t)tok * Dd + col;
                    atomicAdd(op + 0,  w * acc[m][0][g]);
                    atomicAdd(op + 16, w * acc[m][1][g]);
                    atomicAdd(op + 32, w * acc[m][2][g]);
                    atomicAdd(op + 48, w * acc[m][3][g]);
                }
            }
        }
    }
}

// ---------------- Combine: out[t] = w1*P[s1] + w2*P[s2] ----------------
__global__ __launch_bounds__(256) void combine_kernel(
    const float* __restrict__ P, const int* __restrict__ pos,
    const float* __restrict__ tok_w, float* __restrict__ out)
{
    int t = blockIdx.x;
    int d = threadIdx.x * 4;
    int s1 = pos[t * 2], s2 = pos[t * 2 + 1];
    float w1 = tok_w[t * 2], w2 = tok_w[t * 2 + 1];
    float4 a = *(const float4*)(P + (size_t)s1 * Dd + d);
    float4 b = *(const float4*)(P + (size_t)s2 * Dd + d);
    float4 o;
    o.x = w1 * a.x + w2 * b.x; o.y = w1 * a.y + w2 * b.y;
    o.z = w1 * a.z + w2 * b.z; o.w = w1 * a.w + w2 * b.w;
    *(float4*)(out + (size_t)t * Dd + d) = o;
}

// ---------------- Host launch ----------------
extern "C" void kernel_launch(void* const* d_in, const int* in_sizes, int n_in,
                              void* d_out, int out_size, void* d_ws, size_t ws_size,
                              hipStream_t stream)
{
    const float* x     = (const float*)d_in[0];
    const float* gw    = (const float*)d_in[1];
    const float* wgate = (const float*)d_in[2];
    const float* wup   = (const float*)d_in[3];
    const float* wdown = (const float*)d_in[4];
    float* out = (float*)d_out;

    char* ws = (char*)d_ws;
    float* usage_bank = (float*)(ws);
    int*   counts     = (int*)(ws + 2048);
    int*   seg_off    = (int*)(ws + 2112);
    int*   cursor     = (int*)(ws + 2176);
    int*   ntiles     = (int*)(ws + 2240);
    int*   tile_e     = (int*)(ws + 4096);
    int*   tile_row0  = (int*)(ws + 5120);
    int*   tok_i      = (int*)(ws + 8192);
    float* tok_w      = (float*)(ws + 73728);
    int*   token_id   = (int*)(ws + 139264);
    float* pair_w     = (float*)(ws + 204800);
    int*   pos        = (int*)(ws + 270336);
    const size_t CTRL  = 335872;
    const size_t TILEB = (size_t)BMT * Ff * 2;          // 1,441,792 B per h-tile
    const size_t XgB   = (size_t)(Pp + BMT) * Dd * 2;   // 34.1 MB (padded)
    const size_t W1B   = 2ull * Ee * Ff * Dd * 2;       // 92.3 MB interleaved gate/up
    const size_t WDB   = (size_t)Ee * Dd * Ff * 2;      // 46.1 MB
    const size_t PB    = (size_t)Pp * Dd * 4;           // 67.1 MB fp32 per-pair rows

    if (ws_size >= 4096) hipMemsetAsync(ws, 0, 4096, stream);
    size_t fixed = CTRL + XgB + W1B + WDB;
    if (ws_size < fixed + TILEB) {   // cannot run the fast path; fail gracefully (no OOB)
        hipMemsetAsync(d_out, 0, (size_t)out_size * 4, stream);
        return;
    }

    router_kernel<<<Tt / 4, 256, 0, stream>>>(x, gw, usage_bank, counts, tok_i, tok_w);
    scan_kernel<<<1, 64, 0, stream>>>(usage_bank, counts, seg_off, cursor,
                                      ntiles, tile_e, tile_row0, out + (out_size - 1));
    build_kernel<<<Tt / 256, 256, 0, stream>>>(tok_i, tok_w, cursor, token_id, pair_w, pos);

    uint16_t* Xg   = (uint16_t*)(ws + CTRL);
    uint16_t* W1b  = (uint16_t*)(ws + CTRL + XgB);
    uint16_t* wd_b = (uint16_t*)(ws + CTRL + XgB + W1B);
    size_t rem = ws_size - fixed;

    // choose P-buffer mode (store + combine) vs atomic mode
    int TcP = (rem > PB) ? (int)((rem - PB) / TILEB) : 0;
    if (TcP > MAXT) TcP = MAXT;
    bool useP = (TcP >= 24);
    float* Pbuf = nullptr;
    uint16_t* hbuf;
    int Tc;
    if (useP) {
        Pbuf = (float*)(ws + fixed);
        hbuf = (uint16_t*)(ws + fixed + PB);
        Tc = TcP;
    } else {
        hbuf = (uint16_t*)(ws + fixed);
        Tc = (int)(rem / TILEB);
        if (Tc > MAXT) Tc = MAXT;
        hipMemsetAsync(d_out, 0, (size_t)(out_size - 1) * 4, stream);  // atomics need zeroed out
    }
    int nchunks = (MAXT + Tc - 1) / Tc;
    Tc = (MAXT + nchunks - 1) / nchunks;   // even split

    long long n = (long long)Ee * Ff * Dd;
    conv_w1_kernel<<<11264, 256, 0, stream>>>(wgate, wup, W1b);
    conv_kernel<<<11264, 256, 0, stream>>>(wdown, wd_b, n);
    gather_kernel<<<Pp / 4, 256, 0, stream>>>(x, token_id, Xg);

    int nwg1 = Tc * 22;   // 5632/256 n-tiles
    int nwg2 = Tc * 8;    // 1024/128 n-tiles
    for (int c = 0; c < nchunks; ++c) {
        int tile0 = c * Tc;
        gemm_pipe<16, 256, 0><<<nwg1, 512, 0, stream>>>(
            Xg, W1b, seg_off, tile_e, tile_row0, ntiles, token_id, pair_w,
            hbuf, Pbuf, out, tile0, Tc, nwg1);
        if (useP) {
            gemm_pipe<44, 128, 1><<<nwg2, 512, 0, stream>>>(
                hbuf, wd_b, seg_off, tile_e, tile_row0, ntiles, token_id, pair_w,
                hbuf, Pbuf, out, tile0, Tc, nwg2);
        } else {
            gemm_pipe<44, 128, 2><<<nwg2, 512, 0, stream>>>(
                hbuf, wd_b, seg_off, tile_e, tile_row0, ntiles, token_id, pair_w,
                hbuf, Pbuf, out, tile0, Tc, nwg2);
        }
    }
    if (useP)
        combine_kernel<<<Tt, 256, 0, stream>>>(Pbuf, pos, tok_w, out);
}